// Round 11
// baseline (127.303 us; speedup 1.0000x reference)
//
#include <hip/hip_runtime.h>
#include <hip/hip_fp16.h>

typedef float    f32x4 __attribute__((ext_vector_type(4)));
typedef _Float16 f16x8 __attribute__((ext_vector_type(8)));

#define BF_DIM 1024
#define BF_STAGES 10

// f16 (cos,sin) tables: 4 B/pair, 2 KB/stage, 20 KB total.
// Per stage, lane l's 8 needed pairs are packed contiguously at pairs [l*8..l*8+7]:
//   stages 0-3: pos = k (natural order IS lane-contiguous for the reg layout)
//   stages 4-7: k = hi2*128 + j*16 + lo4 -> pos = (hi2*16+lo4)*8 + j   (layout B)
//   stages 8-9: k = g*256 + lane*4 + c   -> pos = lane*8 + g*4 + c     (layout C)
__global__ void bf_fill_cs(const float* __restrict__ angles, unsigned* __restrict__ cs, int n) {
    int i = blockIdx.x * blockDim.x + threadIdx.x;
    if (i >= n) return;
    int s = i >> 9, k = i & 511;
    float a = angles[i];
    float sv, cv;
    sincosf(a, &sv, &cv);
    int pos;
    if (s >= 4 && s < 8) {
        int hi2 = k >> 7, j = (k >> 4) & 7, lo4 = k & 15;
        pos = ((hi2 << 4) | lo4) * 8 + j;
    } else if (s >= 8) {
        pos = ((k & 255) >> 2) * 8 + (k >> 8) * 4 + (k & 3);
    } else {
        pos = k;
    }
    unsigned hc = __half_as_ushort(__float2half_rn(cv));
    unsigned hs = __half_as_ushort(__float2half_rn(sv));
    cs[s * 512 + pos] = (hs << 16) | hc;   // low16 = cos, high16 = sin (LE)
}

#define ROT(vi, vj, c, s) do { float _t = fmaf(-(s), (vj), (c)*(vi)); \
                               (vj) = fmaf((s), (vi), (c)*(vj)); (vi) = _t; } while (0)

// Expand one f16x8 (4 cos/sin pairs) into two f32x4 coeff vecs (c0,s0,c1,s1).
#define EXP(t, ca, cb) do { \
    ca = (f32x4){(float)(t)[0], (float)(t)[1], (float)(t)[2], (float)(t)[3]}; \
    cb = (f32x4){(float)(t)[4], (float)(t)[5], (float)(t)[6], (float)(t)[7]}; } while (0)

// Half-stage ops on a pair of data vecs with 2 coeff vecs (4 pairs).
#define H_EVEN(P, Q, c0, c1) do { \
    ROT(P.x, P.y, c0.x, c0.y); ROT(P.z, P.w, c0.z, c0.w); \
    ROT(Q.x, Q.y, c1.x, c1.y); ROT(Q.z, Q.w, c1.z, c1.w); } while (0)
#define H_ODD(P, Q, c0, c1) do { \
    ROT(P.x, P.z, c0.x, c0.y); ROT(P.y, P.w, c0.z, c0.w); \
    ROT(Q.x, Q.z, c1.x, c1.y); ROT(Q.y, Q.w, c1.z, c1.w); } while (0)
#define H_PAIR(P, Q, c0, c1) do { \
    ROT(P.x, Q.x, c0.x, c0.y); ROT(P.y, Q.y, c0.z, c0.w); \
    ROT(P.z, Q.z, c1.x, c1.y); ROT(P.w, Q.w, c1.z, c1.w); } while (0)

// One full stage (single row) from two HOISTED f16x8 regs.
#define DO_STAGE1(HOP, t0, t1, X0, X1, X2, X3) do { \
    f32x4 _c0, _c1; \
    EXP(t0, _c0, _c1); \
    HOP(X0, X1, _c0, _c1); \
    EXP(t1, _c0, _c1); \
    HOP(X2, X3, _c0, _c1); } while (0)

// Round-11: clean VMEM pipeline. vmcnt is strictly ORDERED, so any load
// issued after stores waits for those stores to retire (r9/r10: next-iter
// loads at loop top = after prev stores -> store completion on the critical
// path every iteration; in-loop table loads made every stage wait on all
// older VMEM too). Fix: per iteration the ONLY VMEM is {4 prefetch loads
// issued BEFORE the 4 stores}; the consume-wait next iteration resolves at
// vmcnt(4) with stores still in flight. Tables: fully hoisted to 80 VGPRs
// (r10) so the body has zero other VMEM. R=1 to fit: 16 data + 16 prefetch
// + 80 table + addressing ~ 124 <= the 128-VGPR budget __launch_bounds__
// (256,2) yields (r2 evidence). Single 5 KB/wave stride-20 slab (r5/r6),
// zero barriers (wave-private, same-wave DS ops pipe-ordered).
__global__ __launch_bounds__(256, 2) void bf_butterfly(const float* __restrict__ x,
                                                       const f16x8* __restrict__ TH,
                                                       float* __restrict__ out,
                                                       int n_rows, int row_stride) {
    __shared__ __align__(16) float lds[4 * 1280];  // 4 waves * 64 lanes * 20 words = 20 KB
    const int lane = threadIdx.x & 63;
    const int wv   = threadIdx.x >> 6;
    float* L = lds + wv * 1280;

    const int wb = lane * 20;                         // layout A base
    const int rb = (lane >> 4) * 320 + (lane & 15);   // layout B base
    const int cb = (lane >> 2) * 20 + (lane & 3) * 4; // layout C base

    int row = blockIdx.x * 4 + wv;
    if (row >= n_rows) return;

    // ---- hoist all 10 stages' coefficients into registers (loop-invariant)
    const f16x8* tp = TH + lane * 2;
    f16x8 TA0 = tp[0 * 128], TB0 = tp[0 * 128 + 1];
    f16x8 TA1 = tp[1 * 128], TB1 = tp[1 * 128 + 1];
    f16x8 TA2 = tp[2 * 128], TB2 = tp[2 * 128 + 1];
    f16x8 TA3 = tp[3 * 128], TB3 = tp[3 * 128 + 1];
    f16x8 TA4 = tp[4 * 128], TB4 = tp[4 * 128 + 1];
    f16x8 TA5 = tp[5 * 128], TB5 = tp[5 * 128 + 1];
    f16x8 TA6 = tp[6 * 128], TB6 = tp[6 * 128 + 1];
    f16x8 TA7 = tp[7 * 128], TB7 = tp[7 * 128 + 1];
    f16x8 TA8 = tp[8 * 128], TB8 = tp[8 * 128 + 1];
    f16x8 TA9 = tp[9 * 128], TB9 = tp[9 * 128 + 1];

    // prime the pipeline
    const float* xp = x + (long long)row * BF_DIM + lane * 16;
    f32x4 P0 = __builtin_nontemporal_load((const f32x4*)(xp + 0));
    f32x4 P1 = __builtin_nontemporal_load((const f32x4*)(xp + 4));
    f32x4 P2 = __builtin_nontemporal_load((const f32x4*)(xp + 8));
    f32x4 P3 = __builtin_nontemporal_load((const f32x4*)(xp + 12));

#pragma unroll 1
    while (true) {
        // consume prefetched row (vmcnt wait lands here; 4 younger stores may fly)
        f32x4 U0 = P0, U1 = P1, U2 = P2, U3 = P3;

        // issue next row's loads NOW -- before any store this iteration
        const int nxt = row + row_stride;
        const bool more = nxt < n_rows;
        const int pre = more ? nxt : row;
        xp = x + (long long)pre * BF_DIM + lane * 16;
        P0 = __builtin_nontemporal_load((const f32x4*)(xp + 0));
        P1 = __builtin_nontemporal_load((const f32x4*)(xp + 4));
        P2 = __builtin_nontemporal_load((const f32x4*)(xp + 8));
        P3 = __builtin_nontemporal_load((const f32x4*)(xp + 12));

        // ---- stages 0-3 (layout A, in regs; tables from VGPRs, zero VMEM)
        DO_STAGE1(H_EVEN, TA0, TB0, U0, U1, U2, U3);
        DO_STAGE1(H_ODD,  TA1, TB1, U0, U1, U2, U3);
        DO_STAGE1(H_PAIR, TA2, TB2, U0, U1, U2, U3);
        DO_STAGE1(H_PAIR, TA3, TB3, U0, U2, U1, U3);  // pairs (0,2),(1,3)

        // ---- transpose 1: write layout A (b128), read layout B (b32); wave-private
        *(f32x4*)(L + wb + 0)  = U0;
        *(f32x4*)(L + wb + 4)  = U1;
        *(f32x4*)(L + wb + 8)  = U2;
        *(f32x4*)(L + wb + 12) = U3;
        U0.x = L[rb + 0 * 20];  U0.y = L[rb + 1 * 20];  U0.z = L[rb + 2 * 20];  U0.w = L[rb + 3 * 20];
        U1.x = L[rb + 4 * 20];  U1.y = L[rb + 5 * 20];  U1.z = L[rb + 6 * 20];  U1.w = L[rb + 7 * 20];
        U2.x = L[rb + 8 * 20];  U2.y = L[rb + 9 * 20];  U2.z = L[rb + 10 * 20]; U2.w = L[rb + 11 * 20];
        U3.x = L[rb + 12 * 20]; U3.y = L[rb + 13 * 20]; U3.z = L[rb + 14 * 20]; U3.w = L[rb + 15 * 20];

        // ---- stages 4-7 (layout B, in regs)
        DO_STAGE1(H_EVEN, TA4, TB4, U0, U1, U2, U3);
        DO_STAGE1(H_ODD,  TA5, TB5, U0, U1, U2, U3);
        DO_STAGE1(H_PAIR, TA6, TB6, U0, U1, U2, U3);
        DO_STAGE1(H_PAIR, TA7, TB7, U0, U2, U1, U3);

        // ---- transpose 2: write layout B back (b32), read layout C (b128)
        L[rb + 0 * 20]  = U0.x; L[rb + 1 * 20]  = U0.y; L[rb + 2 * 20]  = U0.z; L[rb + 3 * 20]  = U0.w;
        L[rb + 4 * 20]  = U1.x; L[rb + 5 * 20]  = U1.y; L[rb + 6 * 20]  = U1.z; L[rb + 7 * 20]  = U1.w;
        L[rb + 8 * 20]  = U2.x; L[rb + 9 * 20]  = U2.y; L[rb + 10 * 20] = U2.z; L[rb + 11 * 20] = U2.w;
        L[rb + 12 * 20] = U3.x; L[rb + 13 * 20] = U3.y; L[rb + 14 * 20] = U3.z; L[rb + 15 * 20] = U3.w;
        U0 = *(const f32x4*)(L + cb);
        U1 = *(const f32x4*)(L + cb + 320);
        U2 = *(const f32x4*)(L + cb + 640);
        U3 = *(const f32x4*)(L + cb + 960);

        // ---- stages 8-9 (layout C, in regs): (V0,V1),(V2,V3) then (V0,V2),(V1,V3)
        DO_STAGE1(H_PAIR, TA8, TB8, U0, U1, U2, U3);
        DO_STAGE1(H_PAIR, TA9, TB9, U0, U2, U1, U3);

        float* orr = out + (long long)row * BF_DIM;
        __builtin_nontemporal_store(U0, (f32x4*)(orr + lane * 4));
        __builtin_nontemporal_store(U1, (f32x4*)(orr + 256 + lane * 4));
        __builtin_nontemporal_store(U2, (f32x4*)(orr + 512 + lane * 4));
        __builtin_nontemporal_store(U3, (f32x4*)(orr + 768 + lane * 4));

        if (!more) break;
        row = nxt;
    }
}

extern "C" void kernel_launch(void* const* d_in, const int* in_sizes, int n_in,
                              void* d_out, int out_size, void* d_ws, size_t ws_size,
                              hipStream_t stream) {
    const float* x      = (const float*)d_in[0];
    const float* angles = (const float*)d_in[1];
    float*       out    = (float*)d_out;
    unsigned*    cs     = (unsigned*)d_ws;  // 10*512*4 = 20480 bytes

    const int ncs = BF_STAGES * (BF_DIM / 2);
    bf_fill_cs<<<(ncs + 255) / 256, 256, 0, stream>>>(angles, cs, ncs);

    const int rows = in_sizes[0] / BF_DIM;
    int blocks = (rows + 3) / 4;
    if (blocks > 1024) blocks = 1024;   // 4 blocks/CU (128-VGPR cap = 16 waves/CU); 16 iters/wave
    const int row_stride = blocks * 4;  // total waves
    bf_butterfly<<<blocks, 256, 0, stream>>>(x, (const f16x8*)cs, out, rows, row_stride);
}